// Round 10
// baseline (753.421 us; speedup 1.0000x reference)
//
#include <hip/hip_runtime.h>
#include <hip/hip_cooperative_groups.h>
#include <stdint.h>

namespace cg = cooperative_groups;

typedef short bh8 __attribute__((ext_vector_type(8)));   // 8 bf16 (4 VGPR)
typedef float f32x4 __attribute__((ext_vector_type(4))); // MFMA accumulator

// ---------- helpers ----------
__device__ __forceinline__ float b2f(unsigned short u) {
    return __uint_as_float(((unsigned int)u) << 16);
}
__device__ __forceinline__ unsigned short f2b(float f) {
    unsigned int x = __float_as_uint(f);
    return (unsigned short)((x + 0x7FFFu + ((x >> 16) & 1u)) >> 16);  // RNE
}
__device__ __forceinline__ float ldf(const void* p, size_t i, int bf) {
    return bf ? b2f(((const unsigned short*)p)[i]) : ((const float*)p)[i];
}
__device__ __forceinline__ int ldi(const int* p, size_t i, int i64f) {
    return i64f ? p[2 * i] : p[i];
}

// ---------- dtype detector + W1/W2 transpose prep (1 block) ----------
__global__ void k_detect(const unsigned short* xs, const int* ei32, int* flags,
                         const void* __restrict__ W1, unsigned short* __restrict__ Wt1,
                         const void* __restrict__ W2, unsigned short* __restrict__ Wt2) {
    __shared__ int bad, nz;
    if (threadIdx.x == 0) { bad = 0; nz = 0; }
    __syncthreads();
    int t = threadIdx.x;
    int b = 0;
    for (int i = t; i < 4096; i += 256) {
        unsigned e = (xs[i] >> 7) & 0xFF;
        if (e >= 0xE2) b = 1;
    }
    if (b) atomicOr(&bad, 1);
    int n = 0;
    for (int i = t; i < 512; i += 256) {
        if (ei32[2 * i + 1] != 0) n = 1;
    }
    if (n) atomicOr(&nz, 1);
    __syncthreads();
    if (t == 0) { flags[0] = bad ? 0 : 1; flags[1] = nz ? 0 : 1; }
    int bf = bad ? 0 : 1;
    for (int idx = t; idx < 16384; idx += 256) {       // Wt1[n][k] = W1[k][n], 128x128
        int k = idx >> 7, nn = idx & 127;
        Wt1[nn * 128 + k] = bf ? ((const unsigned short*)W1)[idx]
                               : f2b(((const float*)W1)[idx]);
    }
    for (int idx = t; idx < 8192; idx += 256) {        // Wt2[n][k] = W2[k][n], k<128,n<64
        int k = idx >> 6, nn = idx & 63;
        Wt2[nn * 128 + k] = bf ? ((const unsigned short*)W2)[idx]
                               : f2b(((const float*)W2)[idx]);
    }
}

// ---------- fused CSR build (cooperative): zero -> hist -> scan -> scatter ----------
__global__ __launch_bounds__(256)
void k_csr(const int* __restrict__ ei, int* __restrict__ counts,
           int* __restrict__ eoff, int* __restrict__ rowptr, int* __restrict__ bsums,
           int* __restrict__ esrc, const int* __restrict__ flags,
           int N, int E, int Et) {
    cg::grid_group grid = cg::this_grid();
    __shared__ int sd[256];
    int gtid = blockIdx.x * 256 + threadIdx.x;
    int gsz = gridDim.x * 256;
    int i64f = flags[1];
    for (int i = gtid; i < N; i += gsz) counts[i] = 0;
    grid.sync();
    for (int e = gtid; e < Et; e += gsz) {
        int d = (e < E) ? ldi(ei, (size_t)E + e, i64f) : (e - E);
        eoff[e] = atomicAdd(&counts[d], 1);
    }
    grid.sync();
    int NBs = (N + 255) / 256;
    for (int blk = blockIdx.x; blk < NBs; blk += gridDim.x) {
        int i = blk * 256 + threadIdx.x;
        int v = (i < N) ? counts[i] : 0;
        sd[threadIdx.x] = v; __syncthreads();
        for (int off = 1; off < 256; off <<= 1) {
            int x = 0;
            if (threadIdx.x >= off) x = sd[threadIdx.x - off];
            __syncthreads();
            if (threadIdx.x >= off) sd[threadIdx.x] += x;
            __syncthreads();
        }
        int incl = sd[threadIdx.x];
        if (i < N) rowptr[i] = incl - v;
        if (threadIdx.x == 255) bsums[blk] = incl;
        __syncthreads();
    }
    grid.sync();
    if (blockIdx.x == 0) {
        int i = threadIdx.x;
        int v = (i < NBs) ? bsums[i] : 0;
        sd[i] = v; __syncthreads();
        for (int off = 1; off < 256; off <<= 1) {
            int x = 0;
            if (i >= off) x = sd[i - off];
            __syncthreads();
            if (i >= off) sd[i] += x;
            __syncthreads();
        }
        if (i < NBs) bsums[i] = sd[i] - v;
    }
    grid.sync();
    for (int i = gtid; i < N; i += gsz) rowptr[i] += bsums[i >> 8];
    if (gtid == 0) rowptr[N] = Et;
    grid.sync();
    for (int e = gtid; e < Et; e += gsz) {
        int s, d;
        if (e < E) { s = ldi(ei, (size_t)e, i64f); d = ldi(ei, (size_t)E + e, i64f); }
        else       { s = d = e - E; }
        esrc[rowptr[d] + eoff[e]] = s;
    }
}

// ---------- layer 1 GEMM, MFMA: xh1 = x @ W1 via D' = Wt1 x^T ----------
__global__ __launch_bounds__(256)
void k_gemm1m(const void* __restrict__ xr, const unsigned short* __restrict__ Wt,
              const void* __restrict__ aSr, const void* __restrict__ aDr,
              unsigned int* __restrict__ xh1b, float* __restrict__ a_src,
              float* __restrict__ a_dst, const int* __restrict__ flags, int N) {
    __shared__ unsigned short Xl[64 * 136];   // +8 pad: 2-way bank alias (free)
    __shared__ unsigned short Wl[128 * 136];
    __shared__ float aSf[128], aDf[128];
    int t = threadIdx.x;
    int bf = flags[0];
    int r0 = blockIdx.x * 64;
    if (t < 128) { aSf[t] = ldf(aSr, t, bf); aDf[t] = ldf(aDr, t, bf); }
    #pragma unroll
    for (int i = 0; i < 8; i++) {             // Wt1: 16384 shorts = 2048 uint4
        int idx = t + 256 * i;
        int row = idx >> 4, c16 = idx & 15;
        *(uint4*)&Wl[row * 136 + c16 * 8] = ((const uint4*)Wt)[idx];
    }
    if (bf) {
        const uint4* Xv = (const uint4*)((const unsigned short*)xr + (size_t)r0 * 128);
        #pragma unroll
        for (int i = 0; i < 4; i++) {         // 64 rows x 16 uint4 = 1024
            int idx = t + 256 * i;
            int row = idx >> 4, c16 = idx & 15;
            uint4 v = (r0 + row < N) ? Xv[idx] : uint4{0, 0, 0, 0};
            *(uint4*)&Xl[row * 136 + c16 * 8] = v;
        }
    } else {
        const float4* Xv = (const float4*)((const float*)xr + (size_t)r0 * 128);
        #pragma unroll
        for (int i = 0; i < 8; i++) {         // 64 rows x 32 float4 = 2048
            int idx = t + 256 * i;
            int row = idx >> 5, c4 = idx & 31;
            float4 v = (r0 + row < N) ? Xv[idx] : float4{0.f, 0.f, 0.f, 0.f};
            uint2 pk;
            pk.x = (unsigned int)f2b(v.x) | ((unsigned int)f2b(v.y) << 16);
            pk.y = (unsigned int)f2b(v.z) | ((unsigned int)f2b(v.w) << 16);
            *(uint2*)&Xl[row * 136 + c4 * 4] = pk;
        }
    }
    __syncthreads();
    int w = t >> 6, lane = t & 63;
    int m16 = lane & 15, quad = lane >> 4;
    f32x4 acc[8];
    #pragma unroll
    for (int ct = 0; ct < 8; ct++) acc[ct] = (f32x4){0.f, 0.f, 0.f, 0.f};
    #pragma unroll
    for (int kb = 0; kb < 4; kb++) {
        bh8 xf = *(const bh8*)&Xl[(w * 16 + m16) * 136 + kb * 32 + quad * 8];
        #pragma unroll
        for (int ct = 0; ct < 8; ct++) {
            bh8 wf = *(const bh8*)&Wl[(ct * 16 + m16) * 136 + kb * 32 + quad * 8];
            acc[ct] = __builtin_amdgcn_mfma_f32_16x16x32_bf16(wf, xf, acc[ct], 0, 0, 0);
        }
    }
    __syncthreads();
    {
        int orow = w * 16 + m16;
        #pragma unroll
        for (int ct = 0; ct < 8; ct++) {
            uint2 pk;
            pk.x = (unsigned int)f2b(acc[ct][0]) | ((unsigned int)f2b(acc[ct][1]) << 16);
            pk.y = (unsigned int)f2b(acc[ct][2]) | ((unsigned int)f2b(acc[ct][3]) << 16);
            *(uint2*)&Xl[orow * 136 + ct * 16 + quad * 4] = pk;
        }
    }
    __syncthreads();
    {
        int r = t >> 2, hp = t & 3;
        if (r0 + r < N) {
            #pragma unroll
            for (int hh = 0; hh < 2; hh++) {
                int h = hp * 2 + hh;
                float s = 0.f, d = 0.f;
                #pragma unroll
                for (int c = 0; c < 16; c++) {
                    float xv = b2f(Xl[r * 136 + h * 16 + c]);
                    s += xv * aSf[h * 16 + c];
                    d += xv * aDf[h * 16 + c];
                }
                a_src[(size_t)(r0 + r) * 8 + h] = s;
                a_dst[(size_t)(r0 + r) * 8 + h] = d;
            }
        }
    }
    #pragma unroll
    for (int i = 0; i < 4; i++) {
        int idx = t + 256 * i;
        int row = idx >> 4, c16 = idx & 15;
        if (r0 + row < N)
            ((uint4*)xh1b)[(size_t)(r0 + row) * 16 + c16] =
                *(const uint4*)&Xl[row * 136 + c16 * 8];
    }
}

// ---------- layer 1 softmax-aggregate: readlane s, saddr gathers, prefetched ----------
__global__ __launch_bounds__(256)
void k_agg1(const int* __restrict__ rowptr, const int* __restrict__ esrc,
            const float* __restrict__ a_src, const float* __restrict__ a_dst,
            const unsigned int* __restrict__ xh1b, const void* __restrict__ b1,
            unsigned int* __restrict__ h1b, const int* __restrict__ flags, int N) {
    int node = blockIdx.x * 4 + (threadIdx.x >> 6);
    int lane = threadIdx.x & 63;
    if (node >= N) return;
    int bf = flags[0];
    int r0 = rowptr[node], r1 = rowptr[node + 1];
    int h8 = lane & 7;
    int q  = lane >> 3;
    float adst = a_dst[node * 8 + h8];
    int pidx = r0 + q;
    bool pval = pidx < r1;
    int   s_next = pval ? esrc[pidx] : 0;
    float a_next = pval ? a_src[(size_t)s_next * 8 + h8] : 0.f;
    float den = 0.f, acc0 = 0.f, acc1 = 0.f;
    for (int e = r0; e < r1; e += 8) {
        int   s_mine = s_next;
        float a_cur  = a_next;
        bool  vcur   = (e + q) < r1;
        int idx2 = e + 8 + q;
        bool v2 = idx2 < r1;
        s_next = v2 ? esrc[idx2] : 0;
        a_next = v2 ? a_src[(size_t)s_next * 8 + h8] : 0.f;
        float v = a_cur + adst;
        v = v > 0.f ? v : 0.2f * v;
        float ex = vcur ? __expf(v) : 0.f;
        den += ex;
        #pragma unroll
        for (int q2 = 0; q2 < 8; q2++) {
            int   s_q  = __builtin_amdgcn_readlane(s_mine, q2 * 8);
            float ex_q = __shfl(ex, q2 * 8 + q);
            const unsigned int* rowp = xh1b + (size_t)s_q * 64;
            unsigned int wv = rowp[lane];
            acc0 += ex_q * b2f((unsigned short)wv);
            acc1 += ex_q * b2f((unsigned short)(wv >> 16));
        }
    }
    den += __shfl_xor(den, 8);
    den += __shfl_xor(den, 16);
    den += __shfl_xor(den, 32);
    float dA = __shfl(den, q) + 1e-16f;
    float o0 = acc0 / dA + ldf(b1, 2 * lane, bf);
    float o1 = acc1 / dA + ldf(b1, 2 * lane + 1, bf);
    o0 = o0 > 0.f ? o0 : expm1f(o0);
    o1 = o1 > 0.f ? o1 : expm1f(o1);
    h1b[(size_t)node * 64 + lane] =
        (unsigned int)f2b(o0) | ((unsigned int)f2b(o1) << 16);
}

// ---------- layer 2 GEMM, MFMA: xh2 = h1 @ W2 via D' = Wt2 h1^T; fused att2 ----------
__global__ __launch_bounds__(256)
void k_gemm2m(const unsigned int* __restrict__ h1b, const unsigned short* __restrict__ Wt2,
              const void* __restrict__ aSr, const void* __restrict__ aDr,
              unsigned int* __restrict__ xh2b, float* __restrict__ a_src,
              float* __restrict__ a_dst, const int* __restrict__ flags, int N) {
    __shared__ unsigned short Xl[64 * 136];
    __shared__ unsigned short Wl[64 * 136];
    __shared__ float aSf[64], aDf[64];
    int t = threadIdx.x;
    int bf = flags[0];
    int r0 = blockIdx.x * 64;
    if (t < 64) { aSf[t] = ldf(aSr, t, bf); aDf[t] = ldf(aDr, t, bf); }
    #pragma unroll
    for (int i = 0; i < 4; i++) {            // Wt2: 64 rows x 16 uint4 = 1024 uint4 (FIXED)
        int idx = t + 256 * i;
        int row = idx >> 4, c16 = idx & 15;
        *(uint4*)&Wl[row * 136 + c16 * 8] = ((const uint4*)Wt2)[idx];
    }
    {
        const uint4* Xv = (const uint4*)h1b;  // bf16 rows, 16 uint4 each
        #pragma unroll
        for (int i = 0; i < 4; i++) {
            int idx = t + 256 * i;
            int row = idx >> 4, c16 = idx & 15;
            uint4 v = (r0 + row < N) ? Xv[(size_t)(r0 + row) * 16 + c16] : uint4{0,0,0,0};
            *(uint4*)&Xl[row * 136 + c16 * 8] = v;
        }
    }
    __syncthreads();
    int w = t >> 6, lane = t & 63;
    int m16 = lane & 15, quad = lane >> 4;
    f32x4 acc[4];
    #pragma unroll
    for (int ct = 0; ct < 4; ct++) acc[ct] = (f32x4){0.f, 0.f, 0.f, 0.f};
    #pragma unroll
    for (int kb = 0; kb < 4; kb++) {
        bh8 xf = *(const bh8*)&Xl[(w * 16 + m16) * 136 + kb * 32 + quad * 8];
        #pragma unroll
        for (int ct = 0; ct < 4; ct++) {
            bh8 wf = *(const bh8*)&Wl[(ct * 16 + m16) * 136 + kb * 32 + quad * 8];
            acc[ct] = __builtin_amdgcn_mfma_f32_16x16x32_bf16(wf, xf, acc[ct], 0, 0, 0);
        }
    }
    // att2 from f32 accumulators: lane holds node m16, chans ct*16+quad*4+r
    float ps = 0.f, pd = 0.f;
    #pragma unroll
    for (int ct = 0; ct < 4; ct++) {
        #pragma unroll
        for (int r = 0; r < 4; r++) {
            int ch = ct * 16 + quad * 4 + r;
            ps += acc[ct][r] * aSf[ch];
            pd += acc[ct][r] * aDf[ch];
        }
    }
    ps += __shfl_xor(ps, 16); ps += __shfl_xor(ps, 32);
    pd += __shfl_xor(pd, 16); pd += __shfl_xor(pd, 32);
    int node = r0 + w * 16 + m16;
    if (node < N) {
        if (quad == 0) { a_src[node] = ps; a_dst[node] = pd; }
        #pragma unroll
        for (int ct = 0; ct < 4; ct++) {
            uint2 pk;
            pk.x = (unsigned int)f2b(acc[ct][0]) | ((unsigned int)f2b(acc[ct][1]) << 16);
            pk.y = (unsigned int)f2b(acc[ct][2]) | ((unsigned int)f2b(acc[ct][3]) << 16);
            *(uint2*)&xh2b[(size_t)node * 32 + ct * 8 + quad * 2] = pk;
        }
    }
}

// ---------- layer 2 softmax-aggregate -> output (readlane s AND ex) ----------
__global__ __launch_bounds__(256)
void k_agg2(const int* __restrict__ rowptr, const int* __restrict__ esrc,
            const float* __restrict__ a_src, const float* __restrict__ a_dst,
            const unsigned int* __restrict__ xh2b, const void* __restrict__ bias,
            void* __restrict__ out, const int* __restrict__ flags, int N) {
    int node = blockIdx.x * 4 + (threadIdx.x >> 6);
    int lane = threadIdx.x & 63;
    if (node >= N) return;
    int bf = flags[0];
    int r0 = rowptr[node], r1 = rowptr[node + 1];
    int q = lane >> 3;
    float adst = a_dst[node];
    const unsigned short* xs = (const unsigned short*)xh2b;
    int pidx = r0 + q;
    bool pval = pidx < r1;
    int   s_next = pval ? esrc[pidx] : 0;
    float a_next = pval ? a_src[s_next] : 0.f;
    float den = 0.f, acc = 0.f;
    for (int e = r0; e < r1; e += 8) {
        int   s_mine = s_next;
        float a_cur  = a_next;
        bool  vcur   = (e + q) < r1;
        int idx2 = e + 8 + q;
        bool v2 = idx2 < r1;
        s_next = v2 ? esrc[idx2] : 0;
        a_next = v2 ? a_src[s_next] : 0.f;
        float v = a_cur + adst;
        v = v > 0.f ? v : 0.2f * v;
        float ex = vcur ? __expf(v) : 0.f;
        den += ex;
        #pragma unroll
        for (int q2 = 0; q2 < 8; q2++) {
            int   s_q  = __builtin_amdgcn_readlane(s_mine, q2 * 8);
            float ex_q = __uint_as_float(
                (unsigned int)__builtin_amdgcn_readlane(__float_as_uint(ex), q2 * 8));
            const unsigned short* rowp = xs + (size_t)s_q * 64;
            acc += ex_q * b2f(rowp[lane]);
        }
    }
    den += __shfl_xor(den, 8);
    den += __shfl_xor(den, 16);
    den += __shfl_xor(den, 32);
    float o = acc / (den + 1e-16f) + ldf(bias, lane, bf);
    size_t oi = (size_t)node * 64 + lane;
    if (bf) ((unsigned short*)out)[oi] = f2b(o);
    else    ((float*)out)[oi] = o;
}

// ---------- launch ----------
extern "C" void kernel_launch(void* const* d_in, const int* in_sizes, int n_in,
                              void* d_out, int out_size, void* d_ws, size_t ws_size,
                              hipStream_t stream) {
    const void* x   = d_in[0];
    const int*  ei  = (const int*)d_in[1];
    const void* W1  = d_in[2];
    const void* aS1 = d_in[3];
    const void* aD1 = d_in[4];
    const void* b1  = d_in[5];
    const void* W2  = d_in[6];
    const void* aS2 = d_in[7];
    const void* aD2 = d_in[8];
    const void* b2v = d_in[9];

    const int N  = in_sizes[0] / 128;   // 50000
    const int E  = in_sizes[1] / 2;     // 800000
    const int Et = E + N;

    char* p = (char*)d_ws;
    auto alloc = [&](size_t bytes) -> char* {
        char* q = p; p += (bytes + 255) & ~(size_t)255; return q;
    };
    unsigned int* xh1b = (unsigned int*)alloc((size_t)N * 64 * 4);
    unsigned int* h1b  = (unsigned int*)alloc((size_t)N * 64 * 4);
    unsigned int* xh2b = (unsigned int*)alloc((size_t)N * 32 * 4);
    float* as1  = (float*)alloc((size_t)N * 8 * 4);
    float* ad1  = (float*)alloc((size_t)N * 8 * 4);
    float* as2  = (float*)alloc((size_t)N * 4);
    float* ad2  = (float*)alloc((size_t)N * 4);
    int* counts = (int*)alloc((size_t)N * 4);
    int* rowptr = (int*)alloc((size_t)(N + 1) * 4);
    int* eoff   = (int*)alloc((size_t)Et * 4);
    int* esrc   = (int*)alloc((size_t)Et * 4);
    int* bsums  = (int*)alloc(256 * 4);
    int* flags  = (int*)alloc(16 * 4);
    unsigned short* Wt1 = (unsigned short*)alloc(128 * 128 * 2);
    unsigned short* Wt2 = (unsigned short*)alloc(64 * 128 * 2);

    k_detect<<<1, 256, 0, stream>>>((const unsigned short*)x, ei, flags, W1, Wt1, W2, Wt2);

    {
        int Nv = N, Ev = E, Etv = Et;
        void* args[] = { (void*)&ei, (void*)&counts, (void*)&eoff, (void*)&rowptr,
                         (void*)&bsums, (void*)&esrc, (void*)&flags,
                         (void*)&Nv, (void*)&Ev, (void*)&Etv };
        hipLaunchCooperativeKernel((const void*)k_csr, dim3(1024), dim3(256),
                                   args, 0, stream);
    }

    k_gemm1m<<<(N + 63) / 64, 256, 0, stream>>>(x, Wt1, aS1, aD1, xh1b, as1, ad1, flags, N);
    k_agg1<<<(N + 3) / 4, 256, 0, stream>>>(rowptr, esrc, as1, ad1, xh1b, b1, h1b, flags, N);
    k_gemm2m<<<(N + 63) / 64, 256, 0, stream>>>(h1b, Wt2, aS2, aD2, xh2b, as2, ad2, flags, N);
    k_agg2<<<(N + 3) / 4, 256, 0, stream>>>(rowptr, esrc, as2, ad2, xh2b, b2v, d_out, flags, N);
}

// Round 11
// 276.557 us; speedup vs baseline: 2.7243x; 2.7243x over previous
//
#include <hip/hip_runtime.h>
#include <stdint.h>

typedef short bh8 __attribute__((ext_vector_type(8)));   // 8 bf16 (4 VGPR)
typedef float f32x4 __attribute__((ext_vector_type(4))); // MFMA accumulator

// ---------- helpers ----------
__device__ __forceinline__ float b2f(unsigned short u) {
    return __uint_as_float(((unsigned int)u) << 16);
}
__device__ __forceinline__ unsigned short f2b(float f) {
    unsigned int x = __float_as_uint(f);
    return (unsigned short)((x + 0x7FFFu + ((x >> 16) & 1u)) >> 16);  // RNE
}
__device__ __forceinline__ float ldf(const void* p, size_t i, int bf) {
    return bf ? b2f(((const unsigned short*)p)[i]) : ((const float*)p)[i];
}
__device__ __forceinline__ int ldi(const int* p, size_t i, int i64f) {
    return i64f ? p[2 * i] : p[i];
}

// ---------- dtype detector + W1/W2 transpose prep (1 block) ----------
__global__ void k_detect(const unsigned short* xs, const int* ei32, int* flags,
                         const void* __restrict__ W1, unsigned short* __restrict__ Wt1,
                         const void* __restrict__ W2, unsigned short* __restrict__ Wt2) {
    __shared__ int bad, nz;
    if (threadIdx.x == 0) { bad = 0; nz = 0; }
    __syncthreads();
    int t = threadIdx.x;
    int b = 0;
    for (int i = t; i < 4096; i += 256) {
        unsigned e = (xs[i] >> 7) & 0xFF;
        if (e >= 0xE2) b = 1;
    }
    if (b) atomicOr(&bad, 1);
    int n = 0;
    for (int i = t; i < 512; i += 256) {
        if (ei32[2 * i + 1] != 0) n = 1;
    }
    if (n) atomicOr(&nz, 1);
    __syncthreads();
    if (t == 0) { flags[0] = bad ? 0 : 1; flags[1] = nz ? 0 : 1; }
    int bf = bad ? 0 : 1;
    for (int idx = t; idx < 16384; idx += 256) {       // Wt1[n][k] = W1[k][n], 128x128
        int k = idx >> 7, nn = idx & 127;
        Wt1[nn * 128 + k] = bf ? ((const unsigned short*)W1)[idx]
                               : f2b(((const float*)W1)[idx]);
    }
    for (int idx = t; idx < 8192; idx += 256) {        // Wt2[n][k] = W2[k][n], k<128,n<64
        int k = idx >> 6, nn = idx & 63;
        Wt2[nn * 128 + k] = bf ? ((const unsigned short*)W2)[idx]
                               : f2b(((const float*)W2)[idx]);
    }
}

// ---------- histogram ----------
__global__ void k_hist(const int* __restrict__ ei, int* __restrict__ counts,
                       int* __restrict__ eoff, const int* __restrict__ flags,
                       int E, int Et) {
    int e = blockIdx.x * 256 + threadIdx.x;
    if (e >= Et) return;
    int i64f = flags[1];
    int d = (e < E) ? ldi(ei, (size_t)E + e, i64f) : (e - E);
    eoff[e] = atomicAdd(&counts[d], 1);
}

// ---------- scan ----------
__global__ void k_scan1(const int* __restrict__ counts, int* __restrict__ excl,
                        int* __restrict__ bsums, int N) {
    __shared__ int sd[256];
    int t = threadIdx.x;
    int base = blockIdx.x * 1024 + t * 4;
    int v0 = (base + 0 < N) ? counts[base + 0] : 0;
    int v1 = (base + 1 < N) ? counts[base + 1] : 0;
    int v2 = (base + 2 < N) ? counts[base + 2] : 0;
    int v3 = (base + 3 < N) ? counts[base + 3] : 0;
    int ls = v0 + v1 + v2 + v3;
    sd[t] = ls; __syncthreads();
    for (int off = 1; off < 256; off <<= 1) {
        int x = 0;
        if (t >= off) x = sd[t - off];
        __syncthreads();
        if (t >= off) sd[t] += x;
        __syncthreads();
    }
    int incl = sd[t];
    int ex = incl - ls;
    if (t == 255) bsums[blockIdx.x] = incl;   // block TOTAL
    if (base + 0 < N) excl[base + 0] = ex; ex += v0;
    if (base + 1 < N) excl[base + 1] = ex; ex += v1;
    if (base + 2 < N) excl[base + 2] = ex; ex += v2;
    if (base + 3 < N) excl[base + 3] = ex;
}

__global__ void k_scan3(int* __restrict__ rowptr, const int* __restrict__ bsums,
                        int N, int Et) {
    int t = threadIdx.x;
    int base = blockIdx.x * 1024 + t * 4;
    int off = 0;
    for (int i = 0; i < (int)blockIdx.x; i++) off += bsums[i];   // <=48 iters
    #pragma unroll
    for (int j = 0; j < 4; j++) { int i = base + j; if (i < N) rowptr[i] += off; }
    if (blockIdx.x == 0 && t == 0) rowptr[N] = Et;
}

// ---------- scatter (atomic-free) ----------
__global__ void k_scatter(const int* __restrict__ ei, const int* __restrict__ rowptr,
                          const int* __restrict__ eoff, int* __restrict__ esrc,
                          const int* __restrict__ flags, int E, int Et) {
    int e = blockIdx.x * 256 + threadIdx.x;
    if (e >= Et) return;
    int i64f = flags[1];
    int s, d;
    if (e < E) { s = ldi(ei, (size_t)e, i64f); d = ldi(ei, (size_t)E + e, i64f); }
    else       { s = d = e - E; }
    esrc[rowptr[d] + eoff[e]] = s;
}

// ---------- layer 1 GEMM, MFMA: xh1 = x @ W1 via D' = Wt1 x^T ----------
__global__ __launch_bounds__(256)
void k_gemm1m(const void* __restrict__ xr, const unsigned short* __restrict__ Wt,
              const void* __restrict__ aSr, const void* __restrict__ aDr,
              unsigned int* __restrict__ xh1b, float* __restrict__ a_src,
              float* __restrict__ a_dst, const int* __restrict__ flags, int N) {
    __shared__ unsigned short Xl[64 * 136];   // +8 pad: 2-way bank alias (free)
    __shared__ unsigned short Wl[128 * 136];
    __shared__ float aSf[128], aDf[128];
    int t = threadIdx.x;
    int bf = flags[0];
    int r0 = blockIdx.x * 64;
    if (t < 128) { aSf[t] = ldf(aSr, t, bf); aDf[t] = ldf(aDr, t, bf); }
    #pragma unroll
    for (int i = 0; i < 8; i++) {             // Wt1: 2048 uint4
        int idx = t + 256 * i;
        int row = idx >> 4, c16 = idx & 15;
        *(uint4*)&Wl[row * 136 + c16 * 8] = ((const uint4*)Wt)[idx];
    }
    if (bf) {
        const uint4* Xv = (const uint4*)((const unsigned short*)xr + (size_t)r0 * 128);
        #pragma unroll
        for (int i = 0; i < 4; i++) {
            int idx = t + 256 * i;
            int row = idx >> 4, c16 = idx & 15;
            uint4 v = (r0 + row < N) ? Xv[idx] : uint4{0, 0, 0, 0};
            *(uint4*)&Xl[row * 136 + c16 * 8] = v;
        }
    } else {
        const float4* Xv = (const float4*)((const float*)xr + (size_t)r0 * 128);
        #pragma unroll
        for (int i = 0; i < 8; i++) {
            int idx = t + 256 * i;
            int row = idx >> 5, c4 = idx & 31;
            float4 v = (r0 + row < N) ? Xv[idx] : float4{0.f, 0.f, 0.f, 0.f};
            uint2 pk;
            pk.x = (unsigned int)f2b(v.x) | ((unsigned int)f2b(v.y) << 16);
            pk.y = (unsigned int)f2b(v.z) | ((unsigned int)f2b(v.w) << 16);
            *(uint2*)&Xl[row * 136 + c4 * 4] = pk;
        }
    }
    __syncthreads();
    int w = t >> 6, lane = t & 63;
    int m16 = lane & 15, quad = lane >> 4;
    f32x4 acc[8];
    #pragma unroll
    for (int ct = 0; ct < 8; ct++) acc[ct] = (f32x4){0.f, 0.f, 0.f, 0.f};
    #pragma unroll
    for (int kb = 0; kb < 4; kb++) {
        bh8 xf = *(const bh8*)&Xl[(w * 16 + m16) * 136 + kb * 32 + quad * 8];
        #pragma unroll
        for (int ct = 0; ct < 8; ct++) {
            bh8 wf = *(const bh8*)&Wl[(ct * 16 + m16) * 136 + kb * 32 + quad * 8];
            acc[ct] = __builtin_amdgcn_mfma_f32_16x16x32_bf16(wf, xf, acc[ct], 0, 0, 0);
        }
    }
    __syncthreads();
    {
        int orow = w * 16 + m16;
        #pragma unroll
        for (int ct = 0; ct < 8; ct++) {
            uint2 pk;
            pk.x = (unsigned int)f2b(acc[ct][0]) | ((unsigned int)f2b(acc[ct][1]) << 16);
            pk.y = (unsigned int)f2b(acc[ct][2]) | ((unsigned int)f2b(acc[ct][3]) << 16);
            *(uint2*)&Xl[orow * 136 + ct * 16 + quad * 4] = pk;
        }
    }
    __syncthreads();
    {
        int r = t >> 2, hp = t & 3;
        if (r0 + r < N) {
            #pragma unroll
            for (int hh = 0; hh < 2; hh++) {
                int h = hp * 2 + hh;
                float s = 0.f, d = 0.f;
                #pragma unroll
                for (int c = 0; c < 16; c++) {
                    float xv = b2f(Xl[r * 136 + h * 16 + c]);
                    s += xv * aSf[h * 16 + c];
                    d += xv * aDf[h * 16 + c];
                }
                a_src[(size_t)(r0 + r) * 8 + h] = s;
                a_dst[(size_t)(r0 + r) * 8 + h] = d;
            }
        }
    }
    #pragma unroll
    for (int i = 0; i < 4; i++) {
        int idx = t + 256 * i;
        int row = idx >> 4, c16 = idx & 15;
        if (r0 + row < N)
            ((uint4*)xh1b)[(size_t)(r0 + row) * 16 + c16] =
                *(const uint4*)&Xl[row * 136 + c16 * 8];
    }
}

// ---------- layer 1 softmax-aggregate: readlane s, saddr gathers, prefetched ----------
__global__ __launch_bounds__(256)
void k_agg1(const int* __restrict__ rowptr, const int* __restrict__ esrc,
            const float* __restrict__ a_src, const float* __restrict__ a_dst,
            const unsigned int* __restrict__ xh1b, const void* __restrict__ b1,
            unsigned int* __restrict__ h1b, const int* __restrict__ flags, int N) {
    int node = blockIdx.x * 4 + (threadIdx.x >> 6);
    int lane = threadIdx.x & 63;
    if (node >= N) return;
    int bf = flags[0];
    int r0 = rowptr[node], r1 = rowptr[node + 1];
    int h8 = lane & 7;
    int q  = lane >> 3;
    float adst = a_dst[node * 8 + h8];
    int pidx = r0 + q;
    bool pval = pidx < r1;
    int   s_next = pval ? esrc[pidx] : 0;
    float a_next = pval ? a_src[(size_t)s_next * 8 + h8] : 0.f;
    float den = 0.f, acc0 = 0.f, acc1 = 0.f;
    for (int e = r0; e < r1; e += 8) {
        int   s_mine = s_next;
        float a_cur  = a_next;
        bool  vcur   = (e + q) < r1;
        int idx2 = e + 8 + q;
        bool v2 = idx2 < r1;
        s_next = v2 ? esrc[idx2] : 0;
        a_next = v2 ? a_src[(size_t)s_next * 8 + h8] : 0.f;
        float v = a_cur + adst;
        v = v > 0.f ? v : 0.2f * v;
        float ex = vcur ? __expf(v) : 0.f;
        den += ex;
        #pragma unroll
        for (int q2 = 0; q2 < 8; q2++) {
            int   s_q  = __builtin_amdgcn_readlane(s_mine, q2 * 8);
            float ex_q = __shfl(ex, q2 * 8 + q);
            const unsigned int* rowp = xh1b + (size_t)s_q * 64;
            unsigned int wv = rowp[lane];
            acc0 += ex_q * b2f((unsigned short)wv);
            acc1 += ex_q * b2f((unsigned short)(wv >> 16));
        }
    }
    den += __shfl_xor(den, 8);
    den += __shfl_xor(den, 16);
    den += __shfl_xor(den, 32);
    float dA = __shfl(den, q) + 1e-16f;
    float o0 = acc0 / dA + ldf(b1, 2 * lane, bf);
    float o1 = acc1 / dA + ldf(b1, 2 * lane + 1, bf);
    o0 = o0 > 0.f ? o0 : expm1f(o0);
    o1 = o1 > 0.f ? o1 : expm1f(o1);
    h1b[(size_t)node * 64 + lane] =
        (unsigned int)f2b(o0) | ((unsigned int)f2b(o1) << 16);
}

// ---------- layer 2 GEMM, MFMA: xh2 = h1 @ W2 via D' = Wt2 h1^T; fused att2 ----------
__global__ __launch_bounds__(256)
void k_gemm2m(const unsigned int* __restrict__ h1b, const unsigned short* __restrict__ Wt2,
              const void* __restrict__ aSr, const void* __restrict__ aDr,
              unsigned int* __restrict__ xh2b, float* __restrict__ a_src,
              float* __restrict__ a_dst, const int* __restrict__ flags, int N) {
    __shared__ unsigned short Xl[64 * 136];
    __shared__ unsigned short Wl[64 * 136];
    __shared__ float aSf[64], aDf[64];
    int t = threadIdx.x;
    int bf = flags[0];
    int r0 = blockIdx.x * 64;
    if (t < 64) { aSf[t] = ldf(aSr, t, bf); aDf[t] = ldf(aDr, t, bf); }
    #pragma unroll
    for (int i = 0; i < 4; i++) {            // Wt2: 64 rows x 16 uint4 = 1024 uint4
        int idx = t + 256 * i;
        int row = idx >> 4, c16 = idx & 15;
        *(uint4*)&Wl[row * 136 + c16 * 8] = ((const uint4*)Wt2)[idx];
    }
    {
        const uint4* Xv = (const uint4*)h1b;  // bf16 rows, 16 uint4 each
        #pragma unroll
        for (int i = 0; i < 4; i++) {
            int idx = t + 256 * i;
            int row = idx >> 4, c16 = idx & 15;
            uint4 v = (r0 + row < N) ? Xv[(size_t)(r0 + row) * 16 + c16] : uint4{0,0,0,0};
            *(uint4*)&Xl[row * 136 + c16 * 8] = v;
        }
    }
    __syncthreads();
    int w = t >> 6, lane = t & 63;
    int m16 = lane & 15, quad = lane >> 4;
    f32x4 acc[4];
    #pragma unroll
    for (int ct = 0; ct < 4; ct++) acc[ct] = (f32x4){0.f, 0.f, 0.f, 0.f};
    #pragma unroll
    for (int kb = 0; kb < 4; kb++) {
        bh8 xf = *(const bh8*)&Xl[(w * 16 + m16) * 136 + kb * 32 + quad * 8];
        #pragma unroll
        for (int ct = 0; ct < 4; ct++) {
            bh8 wf = *(const bh8*)&Wl[(ct * 16 + m16) * 136 + kb * 32 + quad * 8];
            acc[ct] = __builtin_amdgcn_mfma_f32_16x16x32_bf16(wf, xf, acc[ct], 0, 0, 0);
        }
    }
    float ps = 0.f, pd = 0.f;
    #pragma unroll
    for (int ct = 0; ct < 4; ct++) {
        #pragma unroll
        for (int r = 0; r < 4; r++) {
            int ch = ct * 16 + quad * 4 + r;
            ps += acc[ct][r] * aSf[ch];
            pd += acc[ct][r] * aDf[ch];
        }
    }
    ps += __shfl_xor(ps, 16); ps += __shfl_xor(ps, 32);
    pd += __shfl_xor(pd, 16); pd += __shfl_xor(pd, 32);
    int node = r0 + w * 16 + m16;
    if (node < N) {
        if (quad == 0) { a_src[node] = ps; a_dst[node] = pd; }
        #pragma unroll
        for (int ct = 0; ct < 4; ct++) {
            uint2 pk;
            pk.x = (unsigned int)f2b(acc[ct][0]) | ((unsigned int)f2b(acc[ct][1]) << 16);
            pk.y = (unsigned int)f2b(acc[ct][2]) | ((unsigned int)f2b(acc[ct][3]) << 16);
            *(uint2*)&xh2b[(size_t)node * 32 + ct * 8 + quad * 2] = pk;
        }
    }
}

// ---------- layer 2 softmax-aggregate -> output (readlane s AND ex) ----------
__global__ __launch_bounds__(256)
void k_agg2(const int* __restrict__ rowptr, const int* __restrict__ esrc,
            const float* __restrict__ a_src, const float* __restrict__ a_dst,
            const unsigned int* __restrict__ xh2b, const void* __restrict__ bias,
            void* __restrict__ out, const int* __restrict__ flags, int N) {
    int node = blockIdx.x * 4 + (threadIdx.x >> 6);
    int lane = threadIdx.x & 63;
    if (node >= N) return;
    int bf = flags[0];
    int r0 = rowptr[node], r1 = rowptr[node + 1];
    int q = lane >> 3;
    float adst = a_dst[node];
    const unsigned short* xs = (const unsigned short*)xh2b;
    int pidx = r0 + q;
    bool pval = pidx < r1;
    int   s_next = pval ? esrc[pidx] : 0;
    float a_next = pval ? a_src[s_next] : 0.f;
    float den = 0.f, acc = 0.f;
    for (int e = r0; e < r1; e += 8) {
        int   s_mine = s_next;
        float a_cur  = a_next;
        bool  vcur   = (e + q) < r1;
        int idx2 = e + 8 + q;
        bool v2 = idx2 < r1;
        s_next = v2 ? esrc[idx2] : 0;
        a_next = v2 ? a_src[s_next] : 0.f;
        float v = a_cur + adst;
        v = v > 0.f ? v : 0.2f * v;
        float ex = vcur ? __expf(v) : 0.f;
        den += ex;
        #pragma unroll
        for (int q2 = 0; q2 < 8; q2++) {
            int   s_q  = __builtin_amdgcn_readlane(s_mine, q2 * 8);
            float ex_q = __uint_as_float(
                (unsigned int)__builtin_amdgcn_readlane(__float_as_uint(ex), q2 * 8));
            const unsigned short* rowp = xs + (size_t)s_q * 64;
            acc += ex_q * b2f(rowp[lane]);
        }
    }
    den += __shfl_xor(den, 8);
    den += __shfl_xor(den, 16);
    den += __shfl_xor(den, 32);
    float o = acc / (den + 1e-16f) + ldf(bias, lane, bf);
    size_t oi = (size_t)node * 64 + lane;
    if (bf) ((unsigned short*)out)[oi] = f2b(o);
    else    ((float*)out)[oi] = o;
}

// ---------- launch ----------
extern "C" void kernel_launch(void* const* d_in, const int* in_sizes, int n_in,
                              void* d_out, int out_size, void* d_ws, size_t ws_size,
                              hipStream_t stream) {
    const void* x   = d_in[0];
    const int*  ei  = (const int*)d_in[1];
    const void* W1  = d_in[2];
    const void* aS1 = d_in[3];
    const void* aD1 = d_in[4];
    const void* b1  = d_in[5];
    const void* W2  = d_in[6];
    const void* aS2 = d_in[7];
    const void* aD2 = d_in[8];
    const void* b2v = d_in[9];

    const int N  = in_sizes[0] / 128;   // 50000
    const int E  = in_sizes[1] / 2;     // 800000
    const int Et = E + N;

    char* p = (char*)d_ws;
    auto alloc = [&](size_t bytes) -> char* {
        char* q = p; p += (bytes + 255) & ~(size_t)255; return q;
    };
    unsigned int* xh1b = (unsigned int*)alloc((size_t)N * 64 * 4);
    unsigned int* h1b  = (unsigned int*)alloc((size_t)N * 64 * 4);
    unsigned int* xh2b = (unsigned int*)alloc((size_t)N * 32 * 4);
    float* as1  = (float*)alloc((size_t)N * 8 * 4);
    float* ad1  = (float*)alloc((size_t)N * 8 * 4);
    float* as2  = (float*)alloc((size_t)N * 4);
    float* ad2  = (float*)alloc((size_t)N * 4);
    int* counts = (int*)alloc((size_t)N * 4);
    int* rowptr = (int*)alloc((size_t)(N + 1) * 4);
    int* eoff   = (int*)alloc((size_t)Et * 4);
    int* esrc   = (int*)alloc((size_t)Et * 4);
    int* bsums  = (int*)alloc(64 * 4);
    int* flags  = (int*)alloc(16 * 4);
    unsigned short* Wt1 = (unsigned short*)alloc(128 * 128 * 2);
    unsigned short* Wt2 = (unsigned short*)alloc(64 * 128 * 2);

    k_detect<<<1, 256, 0, stream>>>((const unsigned short*)x, ei, flags, W1, Wt1, W2, Wt2);
    hipMemsetAsync(counts, 0, (size_t)N * 4, stream);

    int HB = (Et + 255) / 256;
    k_hist<<<HB, 256, 0, stream>>>(ei, counts, eoff, flags, E, Et);
    int NB = (N + 1023) / 1024;
    k_scan1<<<NB, 256, 0, stream>>>(counts, rowptr, bsums, N);
    k_scan3<<<NB, 256, 0, stream>>>(rowptr, bsums, N, Et);
    k_scatter<<<HB, 256, 0, stream>>>(ei, rowptr, eoff, esrc, flags, E, Et);

    k_gemm1m<<<(N + 63) / 64, 256, 0, stream>>>(x, Wt1, aS1, aD1, xh1b, as1, ad1, flags, N);
    k_agg1<<<(N + 3) / 4, 256, 0, stream>>>(rowptr, esrc, as1, ad1, xh1b, b1, h1b, flags, N);
    k_gemm2m<<<(N + 63) / 64, 256, 0, stream>>>(h1b, Wt2, aS2, aD2, xh2b, as2, ad2, flags, N);
    k_agg2<<<(N + 3) / 4, 256, 0, stream>>>(rowptr, esrc, as2, ad2, xh2b, b2v, d_out, flags, N);
}

// Round 12
// 239.529 us; speedup vs baseline: 3.1454x; 1.1546x over previous
//
#include <hip/hip_runtime.h>
#include <stdint.h>

typedef short bh8 __attribute__((ext_vector_type(8)));   // 8 bf16 (4 VGPR)
typedef float f32x4 __attribute__((ext_vector_type(4))); // MFMA accumulator

// ---------- helpers ----------
__device__ __forceinline__ float b2f(unsigned short u) {
    return __uint_as_float(((unsigned int)u) << 16);
}
__device__ __forceinline__ unsigned short f2b(float f) {
    unsigned int x = __float_as_uint(f);
    return (unsigned short)((x + 0x7FFFu + ((x >> 16) & 1u)) >> 16);  // RNE
}
__device__ __forceinline__ float ldf(const void* p, size_t i, int bf) {
    return bf ? b2f(((const unsigned short*)p)[i]) : ((const float*)p)[i];
}
__device__ __forceinline__ int ldi(const int* p, size_t i, int i64f) {
    return i64f ? p[2 * i] : p[i];
}

// ---------- dtype detector (1 block, flags only) ----------
__global__ void k_detect(const unsigned short* xs, const int* ei32, int* flags) {
    __shared__ int bad, nz;
    if (threadIdx.x == 0) { bad = 0; nz = 0; }
    __syncthreads();
    int t = threadIdx.x;
    int b = 0;
    for (int i = t; i < 4096; i += 256) {
        unsigned e = (xs[i] >> 7) & 0xFF;
        if (e >= 0xE2) b = 1;
    }
    if (b) atomicOr(&bad, 1);
    int n = 0;
    for (int i = t; i < 512; i += 256) {
        if (ei32[2 * i + 1] != 0) n = 1;
    }
    if (n) atomicOr(&nz, 1);
    __syncthreads();
    if (t == 0) { flags[0] = bad ? 0 : 1; flags[1] = nz ? 0 : 1; }
}

// ---------- W1/W2 transpose prep (many blocks, reads flags) ----------
// blocks 0..31: Wt1 (16384 elems, 512/block); blocks 32..47: Wt2 (8192, 512/block)
__global__ void k_prep(const void* __restrict__ W1, unsigned short* __restrict__ Wt1,
                       const void* __restrict__ W2, unsigned short* __restrict__ Wt2,
                       const int* __restrict__ flags) {
    int bf = flags[0];
    int blk = blockIdx.x;
    if (blk < 32) {
        int idx = blk * 512 + threadIdx.x * 2;
        #pragma unroll
        for (int j = 0; j < 2; j++, idx++) {      // Wt1[n][k] = W1[k][n], 128x128
            int k = idx >> 7, nn = idx & 127;
            Wt1[nn * 128 + k] = bf ? ((const unsigned short*)W1)[idx]
                                   : f2b(((const float*)W1)[idx]);
        }
    } else {
        int idx = (blk - 32) * 512 + threadIdx.x * 2;
        #pragma unroll
        for (int j = 0; j < 2; j++, idx++) {      // Wt2[n][k] = W2[k][n], k<128,n<64
            int k = idx >> 6, nn = idx & 63;
            Wt2[nn * 128 + k] = bf ? ((const unsigned short*)W2)[idx]
                                   : f2b(((const float*)W2)[idx]);
        }
    }
}

// ---------- histogram ----------
__global__ void k_hist(const int* __restrict__ ei, int* __restrict__ counts,
                       int* __restrict__ eoff, const int* __restrict__ flags,
                       int E, int Et) {
    int e = blockIdx.x * 256 + threadIdx.x;
    if (e >= Et) return;
    int i64f = flags[1];
    int d = (e < E) ? ldi(ei, (size_t)E + e, i64f) : (e - E);
    eoff[e] = atomicAdd(&counts[d], 1);
}

// ---------- scan ----------
__global__ void k_scan1(const int* __restrict__ counts, int* __restrict__ excl,
                        int* __restrict__ bsums, int N) {
    __shared__ int sd[256];
    int t = threadIdx.x;
    int base = blockIdx.x * 1024 + t * 4;
    int v0 = (base + 0 < N) ? counts[base + 0] : 0;
    int v1 = (base + 1 < N) ? counts[base + 1] : 0;
    int v2 = (base + 2 < N) ? counts[base + 2] : 0;
    int v3 = (base + 3 < N) ? counts[base + 3] : 0;
    int ls = v0 + v1 + v2 + v3;
    sd[t] = ls; __syncthreads();
    for (int off = 1; off < 256; off <<= 1) {
        int x = 0;
        if (t >= off) x = sd[t - off];
        __syncthreads();
        if (t >= off) sd[t] += x;
        __syncthreads();
    }
    int incl = sd[t];
    int ex = incl - ls;
    if (t == 255) bsums[blockIdx.x] = incl;   // block TOTAL
    if (base + 0 < N) excl[base + 0] = ex; ex += v0;
    if (base + 1 < N) excl[base + 1] = ex; ex += v1;
    if (base + 2 < N) excl[base + 2] = ex; ex += v2;
    if (base + 3 < N) excl[base + 3] = ex;
}

__global__ void k_scan3(int* __restrict__ rowptr, const int* __restrict__ bsums,
                        int N, int Et) {
    int t = threadIdx.x;
    int base = blockIdx.x * 1024 + t * 4;
    int off = 0;
    for (int i = 0; i < (int)blockIdx.x; i++) off += bsums[i];   // <=48 iters
    #pragma unroll
    for (int j = 0; j < 4; j++) { int i = base + j; if (i < N) rowptr[i] += off; }
    if (blockIdx.x == 0 && t == 0) rowptr[N] = Et;
}

// ---------- scatter (atomic-free) ----------
__global__ void k_scatter(const int* __restrict__ ei, const int* __restrict__ rowptr,
                          const int* __restrict__ eoff, int* __restrict__ esrc,
                          const int* __restrict__ flags, int E, int Et) {
    int e = blockIdx.x * 256 + threadIdx.x;
    if (e >= Et) return;
    int i64f = flags[1];
    int s, d;
    if (e < E) { s = ldi(ei, (size_t)e, i64f); d = ldi(ei, (size_t)E + e, i64f); }
    else       { s = d = e - E; }
    esrc[rowptr[d] + eoff[e]] = s;
}

// ---------- layer 1 GEMM, MFMA: xh1 = x @ W1 via D' = Wt1 x^T ----------
__global__ __launch_bounds__(256)
void k_gemm1m(const void* __restrict__ xr, const unsigned short* __restrict__ Wt,
              const void* __restrict__ aSr, const void* __restrict__ aDr,
              unsigned int* __restrict__ xh1b, float* __restrict__ a_src,
              float* __restrict__ a_dst, const int* __restrict__ flags, int N) {
    __shared__ unsigned short Xl[64 * 136];   // +8 pad: 2-way bank alias (free)
    __shared__ unsigned short Wl[128 * 136];
    __shared__ float aSf[128], aDf[128];
    int t = threadIdx.x;
    int bf = flags[0];
    int r0 = blockIdx.x * 64;
    if (t < 128) { aSf[t] = ldf(aSr, t, bf); aDf[t] = ldf(aDr, t, bf); }
    #pragma unroll
    for (int i = 0; i < 8; i++) {             // Wt1: 2048 uint4
        int idx = t + 256 * i;
        int row = idx >> 4, c16 = idx & 15;
        *(uint4*)&Wl[row * 136 + c16 * 8] = ((const uint4*)Wt)[idx];
    }
    if (bf) {
        const uint4* Xv = (const uint4*)((const unsigned short*)xr + (size_t)r0 * 128);
        #pragma unroll
        for (int i = 0; i < 4; i++) {
            int idx = t + 256 * i;
            int row = idx >> 4, c16 = idx & 15;
            uint4 v = (r0 + row < N) ? Xv[idx] : uint4{0, 0, 0, 0};
            *(uint4*)&Xl[row * 136 + c16 * 8] = v;
        }
    } else {
        const float4* Xv = (const float4*)((const float*)xr + (size_t)r0 * 128);
        #pragma unroll
        for (int i = 0; i < 8; i++) {
            int idx = t + 256 * i;
            int row = idx >> 5, c4 = idx & 31;
            float4 v = (r0 + row < N) ? Xv[idx] : float4{0.f, 0.f, 0.f, 0.f};
            uint2 pk;
            pk.x = (unsigned int)f2b(v.x) | ((unsigned int)f2b(v.y) << 16);
            pk.y = (unsigned int)f2b(v.z) | ((unsigned int)f2b(v.w) << 16);
            *(uint2*)&Xl[row * 136 + c4 * 4] = pk;
        }
    }
    __syncthreads();
    int w = t >> 6, lane = t & 63;
    int m16 = lane & 15, quad = lane >> 4;
    f32x4 acc[8];
    #pragma unroll
    for (int ct = 0; ct < 8; ct++) acc[ct] = (f32x4){0.f, 0.f, 0.f, 0.f};
    #pragma unroll
    for (int kb = 0; kb < 4; kb++) {
        bh8 xf = *(const bh8*)&Xl[(w * 16 + m16) * 136 + kb * 32 + quad * 8];
        #pragma unroll
        for (int ct = 0; ct < 8; ct++) {
            bh8 wf = *(const bh8*)&Wl[(ct * 16 + m16) * 136 + kb * 32 + quad * 8];
            acc[ct] = __builtin_amdgcn_mfma_f32_16x16x32_bf16(wf, xf, acc[ct], 0, 0, 0);
        }
    }
    __syncthreads();
    {
        int orow = w * 16 + m16;
        #pragma unroll
        for (int ct = 0; ct < 8; ct++) {
            uint2 pk;
            pk.x = (unsigned int)f2b(acc[ct][0]) | ((unsigned int)f2b(acc[ct][1]) << 16);
            pk.y = (unsigned int)f2b(acc[ct][2]) | ((unsigned int)f2b(acc[ct][3]) << 16);
            *(uint2*)&Xl[orow * 136 + ct * 16 + quad * 4] = pk;
        }
    }
    __syncthreads();
    {
        int r = t >> 2, hp = t & 3;
        if (r0 + r < N) {
            #pragma unroll
            for (int hh = 0; hh < 2; hh++) {
                int h = hp * 2 + hh;
                float s = 0.f, d = 0.f;
                #pragma unroll
                for (int c = 0; c < 16; c++) {
                    float xv = b2f(Xl[r * 136 + h * 16 + c]);
                    s += xv * aSf[h * 16 + c];
                    d += xv * aDf[h * 16 + c];
                }
                a_src[(size_t)(r0 + r) * 8 + h] = s;
                a_dst[(size_t)(r0 + r) * 8 + h] = d;
            }
        }
    }
    #pragma unroll
    for (int i = 0; i < 4; i++) {
        int idx = t + 256 * i;
        int row = idx >> 4, c16 = idx & 15;
        if (r0 + row < N)
            ((uint4*)xh1b)[(size_t)(r0 + row) * 16 + c16] =
                *(const uint4*)&Xl[row * 136 + c16 * 8];
    }
}

// ---------- layer 1 softmax-aggregate: readlane s, saddr gathers, prefetched ----------
__global__ __launch_bounds__(256)
void k_agg1(const int* __restrict__ rowptr, const int* __restrict__ esrc,
            const float* __restrict__ a_src, const float* __restrict__ a_dst,
            const unsigned int* __restrict__ xh1b, const void* __restrict__ b1,
            unsigned int* __restrict__ h1b, const int* __restrict__ flags, int N) {
    int node = blockIdx.x * 4 + (threadIdx.x >> 6);
    int lane = threadIdx.x & 63;
    if (node >= N) return;
    int bf = flags[0];
    int r0 = rowptr[node], r1 = rowptr[node + 1];
    int h8 = lane & 7;
    int q  = lane >> 3;
    float adst = a_dst[node * 8 + h8];
    int pidx = r0 + q;
    bool pval = pidx < r1;
    int   s_next = pval ? esrc[pidx] : 0;
    float a_next = pval ? a_src[(size_t)s_next * 8 + h8] : 0.f;
    float den = 0.f, acc0 = 0.f, acc1 = 0.f;
    for (int e = r0; e < r1; e += 8) {
        int   s_mine = s_next;
        float a_cur  = a_next;
        bool  vcur   = (e + q) < r1;
        int idx2 = e + 8 + q;
        bool v2 = idx2 < r1;
        s_next = v2 ? esrc[idx2] : 0;
        a_next = v2 ? a_src[(size_t)s_next * 8 + h8] : 0.f;
        float v = a_cur + adst;
        v = v > 0.f ? v : 0.2f * v;
        float ex = vcur ? __expf(v) : 0.f;
        den += ex;
        #pragma unroll
        for (int q2 = 0; q2 < 8; q2++) {
            int   s_q  = __builtin_amdgcn_readlane(s_mine, q2 * 8);
            float ex_q = __shfl(ex, q2 * 8 + q);
            const unsigned int* rowp = xh1b + (size_t)s_q * 64;
            unsigned int wv = rowp[lane];
            acc0 += ex_q * b2f((unsigned short)wv);
            acc1 += ex_q * b2f((unsigned short)(wv >> 16));
        }
    }
    den += __shfl_xor(den, 8);
    den += __shfl_xor(den, 16);
    den += __shfl_xor(den, 32);
    float dA = __shfl(den, q) + 1e-16f;
    float o0 = acc0 / dA + ldf(b1, 2 * lane, bf);
    float o1 = acc1 / dA + ldf(b1, 2 * lane + 1, bf);
    o0 = o0 > 0.f ? o0 : expm1f(o0);
    o1 = o1 > 0.f ? o1 : expm1f(o1);
    h1b[(size_t)node * 64 + lane] =
        (unsigned int)f2b(o0) | ((unsigned int)f2b(o1) << 16);
}

// ---------- layer 2 GEMM, MFMA: xh2 = h1 @ W2 via D' = Wt2 h1^T; fused att2 ----------
__global__ __launch_bounds__(256)
void k_gemm2m(const unsigned int* __restrict__ h1b, const unsigned short* __restrict__ Wt2,
              const void* __restrict__ aSr, const void* __restrict__ aDr,
              unsigned int* __restrict__ xh2b, float* __restrict__ a_src,
              float* __restrict__ a_dst, const int* __restrict__ flags, int N) {
    __shared__ unsigned short Xl[64 * 136];
    __shared__ unsigned short Wl[64 * 136];
    __shared__ float aSf[64], aDf[64];
    int t = threadIdx.x;
    int bf = flags[0];
    int r0 = blockIdx.x * 64;
    if (t < 64) { aSf[t] = ldf(aSr, t, bf); aDf[t] = ldf(aDr, t, bf); }
    #pragma unroll
    for (int i = 0; i < 4; i++) {            // Wt2: 64 rows x 16 uint4 = 1024 uint4
        int idx = t + 256 * i;
        int row = idx >> 4, c16 = idx & 15;
        *(uint4*)&Wl[row * 136 + c16 * 8] = ((const uint4*)Wt2)[idx];
    }
    {
        const uint4* Xv = (const uint4*)h1b;  // bf16 rows, 16 uint4 each
        #pragma unroll
        for (int i = 0; i < 4; i++) {
            int idx = t + 256 * i;
            int row = idx >> 4, c16 = idx & 15;
            uint4 v = (r0 + row < N) ? Xv[(size_t)(r0 + row) * 16 + c16] : uint4{0,0,0,0};
            *(uint4*)&Xl[row * 136 + c16 * 8] = v;
        }
    }
    __syncthreads();
    int w = t >> 6, lane = t & 63;
    int m16 = lane & 15, quad = lane >> 4;
    f32x4 acc[4];
    #pragma unroll
    for (int ct = 0; ct < 4; ct++) acc[ct] = (f32x4){0.f, 0.f, 0.f, 0.f};
    #pragma unroll
    for (int kb = 0; kb < 4; kb++) {
        bh8 xf = *(const bh8*)&Xl[(w * 16 + m16) * 136 + kb * 32 + quad * 8];
        #pragma unroll
        for (int ct = 0; ct < 4; ct++) {
            bh8 wf = *(const bh8*)&Wl[(ct * 16 + m16) * 136 + kb * 32 + quad * 8];
            acc[ct] = __builtin_amdgcn_mfma_f32_16x16x32_bf16(wf, xf, acc[ct], 0, 0, 0);
        }
    }
    float ps = 0.f, pd = 0.f;
    #pragma unroll
    for (int ct = 0; ct < 4; ct++) {
        #pragma unroll
        for (int r = 0; r < 4; r++) {
            int ch = ct * 16 + quad * 4 + r;
            ps += acc[ct][r] * aSf[ch];
            pd += acc[ct][r] * aDf[ch];
        }
    }
    ps += __shfl_xor(ps, 16); ps += __shfl_xor(ps, 32);
    pd += __shfl_xor(pd, 16); pd += __shfl_xor(pd, 32);
    int node = r0 + w * 16 + m16;
    if (node < N) {
        if (quad == 0) { a_src[node] = ps; a_dst[node] = pd; }
        #pragma unroll
        for (int ct = 0; ct < 4; ct++) {
            uint2 pk;
            pk.x = (unsigned int)f2b(acc[ct][0]) | ((unsigned int)f2b(acc[ct][1]) << 16);
            pk.y = (unsigned int)f2b(acc[ct][2]) | ((unsigned int)f2b(acc[ct][3]) << 16);
            *(uint2*)&xh2b[(size_t)node * 32 + ct * 8 + quad * 2] = pk;
        }
    }
}

// ---------- layer 2 softmax-aggregate -> output (readlane s AND ex) ----------
__global__ __launch_bounds__(256)
void k_agg2(const int* __restrict__ rowptr, const int* __restrict__ esrc,
            const float* __restrict__ a_src, const float* __restrict__ a_dst,
            const unsigned int* __restrict__ xh2b, const void* __restrict__ bias,
            void* __restrict__ out, const int* __restrict__ flags, int N) {
    int node = blockIdx.x * 4 + (threadIdx.x >> 6);
    int lane = threadIdx.x & 63;
    if (node >= N) return;
    int bf = flags[0];
    int r0 = rowptr[node], r1 = rowptr[node + 1];
    int q = lane >> 3;
    float adst = a_dst[node];
    const unsigned short* xs = (const unsigned short*)xh2b;
    int pidx = r0 + q;
    bool pval = pidx < r1;
    int   s_next = pval ? esrc[pidx] : 0;
    float a_next = pval ? a_src[s_next] : 0.f;
    float den = 0.f, acc = 0.f;
    for (int e = r0; e < r1; e += 8) {
        int   s_mine = s_next;
        float a_cur  = a_next;
        bool  vcur   = (e + q) < r1;
        int idx2 = e + 8 + q;
        bool v2 = idx2 < r1;
        s_next = v2 ? esrc[idx2] : 0;
        a_next = v2 ? a_src[s_next] : 0.f;
        float v = a_cur + adst;
        v = v > 0.f ? v : 0.2f * v;
        float ex = vcur ? __expf(v) : 0.f;
        den += ex;
        #pragma unroll
        for (int q2 = 0; q2 < 8; q2++) {
            int   s_q  = __builtin_amdgcn_readlane(s_mine, q2 * 8);
            float ex_q = __uint_as_float(
                (unsigned int)__builtin_amdgcn_readlane(__float_as_uint(ex), q2 * 8));
            const unsigned short* rowp = xs + (size_t)s_q * 64;
            acc += ex_q * b2f(rowp[lane]);
        }
    }
    den += __shfl_xor(den, 8);
    den += __shfl_xor(den, 16);
    den += __shfl_xor(den, 32);
    float o = acc / (den + 1e-16f) + ldf(bias, lane, bf);
    size_t oi = (size_t)node * 64 + lane;
    if (bf) ((unsigned short*)out)[oi] = f2b(o);
    else    ((float*)out)[oi] = o;
}

// ---------- launch ----------
extern "C" void kernel_launch(void* const* d_in, const int* in_sizes, int n_in,
                              void* d_out, int out_size, void* d_ws, size_t ws_size,
                              hipStream_t stream) {
    const void* x   = d_in[0];
    const int*  ei  = (const int*)d_in[1];
    const void* W1  = d_in[2];
    const void* aS1 = d_in[3];
    const void* aD1 = d_in[4];
    const void* b1  = d_in[5];
    const void* W2  = d_in[6];
    const void* aS2 = d_in[7];
    const void* aD2 = d_in[8];
    const void* b2v = d_in[9];

    const int N  = in_sizes[0] / 128;   // 50000
    const int E  = in_sizes[1] / 2;     // 800000
    const int Et = E + N;

    char* p = (char*)d_ws;
    auto alloc = [&](size_t bytes) -> char* {
        char* q = p; p += (bytes + 255) & ~(size_t)255; return q;
    };
    unsigned int* xh1b = (unsigned int*)alloc((size_t)N * 64 * 4);
    unsigned int* h1b  = (unsigned int*)alloc((size_t)N * 64 * 4);
    unsigned int* xh2b = (unsigned int*)alloc((size_t)N * 32 * 4);
    float* as1  = (float*)alloc((size_t)N * 8 * 4);
    float* ad1  = (float*)alloc((size_t)N * 8 * 4);
    float* as2  = (float*)alloc((size_t)N * 4);
    float* ad2  = (float*)alloc((size_t)N * 4);
    int* counts = (int*)alloc((size_t)N * 4);
    int* rowptr = (int*)alloc((size_t)(N + 1) * 4);
    int* eoff   = (int*)alloc((size_t)Et * 4);
    int* esrc   = (int*)alloc((size_t)Et * 4);
    int* bsums  = (int*)alloc(64 * 4);
    int* flags  = (int*)alloc(16 * 4);
    unsigned short* Wt1 = (unsigned short*)alloc(128 * 128 * 2);
    unsigned short* Wt2 = (unsigned short*)alloc(64 * 128 * 2);

    k_detect<<<1, 256, 0, stream>>>((const unsigned short*)x, ei, flags);
    hipMemsetAsync(counts, 0, (size_t)N * 4, stream);
    k_prep<<<48, 256, 0, stream>>>(W1, Wt1, W2, Wt2, flags);

    int HB = (Et + 255) / 256;
    k_hist<<<HB, 256, 0, stream>>>(ei, counts, eoff, flags, E, Et);
    int NB = (N + 1023) / 1024;
    k_scan1<<<NB, 256, 0, stream>>>(counts, rowptr, bsums, N);
    k_scan3<<<NB, 256, 0, stream>>>(rowptr, bsums, N, Et);
    k_scatter<<<HB, 256, 0, stream>>>(ei, rowptr, eoff, esrc, flags, E, Et);

    k_gemm1m<<<(N + 63) / 64, 256, 0, stream>>>(x, Wt1, aS1, aD1, xh1b, as1, ad1, flags, N);
    k_agg1<<<(N + 3) / 4, 256, 0, stream>>>(rowptr, esrc, as1, ad1, xh1b, b1, h1b, flags, N);
    k_gemm2m<<<(N + 63) / 64, 256, 0, stream>>>(h1b, Wt2, aS2, aD2, xh2b, as2, ad2, flags, N);
    k_agg2<<<(N + 3) / 4, 256, 0, stream>>>(rowptr, esrc, as2, ad2, xh2b, b2v, d_out, flags, N);
}